// Round 10
// baseline (222.873 us; speedup 1.0000x reference)
//
#include <hip/hip_runtime.h>
#include <hip/hip_bf16.h>

#define NMODELS 64
#define BBATCH  4096
#define IN_DIM  64
#define H_DIM   256

typedef __attribute__((ext_vector_type(8))) short short8;
typedef __attribute__((ext_vector_type(4))) float floatx4;
typedef __attribute__((ext_vector_type(4))) unsigned int uint4v;
typedef __attribute__((ext_vector_type(2))) unsigned int uint2v;

__device__ __forceinline__ unsigned short f2bf(float f) {   // prep only
    unsigned int u = __builtin_bit_cast(unsigned int, f);
    return (unsigned short)((u + 0x8000u) >> 16);
}
// packed fp32x2 -> bf16x2 (v_cvt_pk_bf16_f32 on gfx950), RNE
__device__ __forceinline__ unsigned int pkbf(float a, float b) {
    __hip_bfloat162 h = __float22bfloat162_rn(make_float2(a, b));
    unsigned int u;
    __builtin_memcpy(&u, &h, 4);
    return u;
}

// Transpose+cvt: W1 [M][64][256]->w1t [M][256][64] bf16 (blocks 0..255)
//                W2 [M][256][256]->w2t [M][256][256] bf16 (blocks 256..1279)
__global__ __launch_bounds__(256) void prep_weights(const float* __restrict__ W1,
                                                    const float* __restrict__ W2,
                                                    unsigned short* __restrict__ w1t,
                                                    unsigned short* __restrict__ w2t) {
    __shared__ float lds[64][65];
    const int bid = blockIdx.x;
    const float* src;
    unsigned short* dst;
    int K, N, m, kb, nb;
    if (bid < 256) {
        m = bid >> 2; kb = 0; nb = bid & 3; K = IN_DIM; N = H_DIM;
        src = W1; dst = w1t;
    } else {
        int t = bid - 256;
        m = t >> 4; kb = (t >> 2) & 3; nb = t & 3; K = H_DIM; N = H_DIM;
        src = W2; dst = w2t;
    }
    const float* s = src + ((size_t)m * K + (size_t)kb * 64) * N + nb * 64;
    const int tid = threadIdx.x;
    const int r = tid >> 4, c4 = (tid & 15) * 4;
#pragma unroll
    for (int p = 0; p < 4; ++p) {
        int row = p * 16 + r;                      // k-local 0..63
        float4 v = *(const float4*)(s + (size_t)row * N + c4);
        lds[row][c4] = v.x; lds[row][c4 + 1] = v.y;
        lds[row][c4 + 2] = v.z; lds[row][c4 + 3] = v.w;
    }
    __syncthreads();
    unsigned short* dbase = dst + ((size_t)m * N + (size_t)nb * 64) * K + kb * 64;
    const int j = tid & 7;                         // k-chunk 0..7
#pragma unroll
    for (int it = 0; it < 2; ++it) {
        int n = it * 32 + (tid >> 3);              // n-local 0..63
        unsigned short tmp[8];
#pragma unroll
        for (int e = 0; e < 8; ++e) tmp[e] = f2bf(lds[j * 8 + e][n]);
        *(short8*)(dbase + (size_t)n * K + j * 8) = *(const short8*)tmp;
    }
}

// Fused 3-layer MLP, T=2-SEQUENTIAL: 2 tiles per WG (amortization preserved)
// but phase1->phase2 run per tile through ONE 32 KB h1 buffer. vs the 84us
// champion (h1s[2]=64KB, acc 128 AGPR -> LDS- AND reg-pinned at 2 WG/CU):
// LDS 34 KB and acc 64 AGPR -> total unified regs ~150-170 ->
// __launch_bounds__(256,3) = 12 waves/CU (+50% latency hiding).
// Costs: 4 barriers/WG (was 2), bv loads per tile-phase (L2-hot after XCD
// swizzle, ping-pong covered), t1's x loaded during t0's phase-3 where acc
// is DEAD (sched_barrier-pinned; the R3/R5 spill trap avoided: xr never
// coexists with live acc). Keeps: XCD-bijective swizzle, setprio, swizzled
// h1 LDS, separate red slab.
__global__ __launch_bounds__(256, 3) void mlp_fused(
    const float* __restrict__ xs,
    const unsigned short* __restrict__ w1t,   // [M][H][IN] bf16
    const float* __restrict__ b1,
    const unsigned short* __restrict__ w2t,   // [M][H][H] bf16 (n-major)
    const float* __restrict__ b2,
    const float* __restrict__ w3,             // [M][H]
    const float* __restrict__ b3,             // [M]
    float* __restrict__ out)                  // [M][B]
{
    __shared__ unsigned short h1s[64 * 256];      // 32 KB, reused by both tiles
    __shared__ float red[2 * 256];                // 2 KB separate slab

    const int bid = blockIdx.x;
    const int wg  = (bid & 7) * 256 + (bid >> 3); // XCD-bijective (2048 = 8*256)
    const int m     = wg >> 5;
    const int tile0 = (wg & 31) * 2;
    const int tid = threadIdx.x;
    const int w   = tid >> 6;
    const int lane = tid & 63;
    const int q   = lane >> 4;
    const int c16 = lane & 15;
    const int sw  = c16 & 7;

    floatx4 b1v = *(const floatx4*)(b1 + m * H_DIM + w * 64 + c16 * 4);

    const float* xrow0 = xs + ((size_t)m * BBATCH + (size_t)tile0 * 64) * IN_DIM;
    const unsigned short* w1p = w1t + (size_t)m * (H_DIM * IN_DIM)
                                + (w * 64 + c16 * 4) * IN_DIM + q * 8;
    const unsigned short* w2p = w2t + (size_t)m * (H_DIM * H_DIM)
                                + (w * 64 + c16 * 4) * H_DIM + q * 8;

    float4 xr[4][2][2];                           // t1 x staging (acc-dead region only)
    float p[2][4][4];                             // phase-3 partials, both tiles
    floatx4 b2v, w3v;
    float b3v;

#pragma unroll
    for (int t = 0; t < 2; ++t) {
        // ---- A-fragments for this tile ----
        short8 ax[4][2];
        if (t == 0) {
#pragma unroll
            for (int rb = 0; rb < 4; ++rb)
#pragma unroll
                for (int kb = 0; kb < 2; ++kb) {
                    const float* xp = xrow0 + (rb * 16 + c16) * IN_DIM + kb * 32 + q * 8;
                    float4 v0 = *(const float4*)xp;
                    float4 v1 = *(const float4*)(xp + 4);
                    uint4v u;
                    u[0] = pkbf(v0.x, v0.y); u[1] = pkbf(v0.z, v0.w);
                    u[2] = pkbf(v1.x, v1.y); u[3] = pkbf(v1.z, v1.w);
                    ax[rb][kb] = __builtin_bit_cast(short8, u);
                }
        } else {
#pragma unroll
            for (int rb = 0; rb < 4; ++rb)
#pragma unroll
                for (int kb = 0; kb < 2; ++kb) {  // xr loaded during t0 phase 3
                    const float4 v0 = xr[rb][kb][0], v1 = xr[rb][kb][1];
                    uint4v u;
                    u[0] = pkbf(v0.x, v0.y); u[1] = pkbf(v0.z, v0.w);
                    u[2] = pkbf(v1.x, v1.y); u[3] = pkbf(v1.z, v1.w);
                    ax[rb][kb] = __builtin_bit_cast(short8, u);
                }
        }

        // ---- Phase 1: h1 = relu(x @ W1 + b1) ----
        floatx4 acc[4][4];
#pragma unroll
        for (int rb = 0; rb < 4; ++rb)
#pragma unroll
            for (int nb = 0; nb < 4; ++nb)
                acc[rb][nb] = (floatx4){0.f, 0.f, 0.f, 0.f};
#pragma unroll
        for (int kb = 0; kb < 2; ++kb) {          // bw per-kb: 16 regs live, not 32
            short8 bw[4];
#pragma unroll
            for (int nb = 0; nb < 4; ++nb)
                bw[nb] = *(const short8*)(w1p + nb * IN_DIM + kb * 32);
            __builtin_amdgcn_s_setprio(1);
#pragma unroll
            for (int nb = 0; nb < 4; ++nb)
#pragma unroll
                for (int rb = 0; rb < 4; ++rb)
                    acc[rb][nb] = __builtin_amdgcn_mfma_f32_16x16x32_bf16(
                        ax[rb][kb], bw[nb], acc[rb][nb], 0, 0, 0);
            __builtin_amdgcn_s_setprio(0);
        }

        // bv ping-pong prologue (h1-independent): overlaps epilogue + barrier
        short8 bv[2][4];
#pragma unroll
        for (int nb = 0; nb < 4; ++nb)
            bv[0][nb] = *(const short8*)(w2p + nb * H_DIM);

        if (t == 0) {                             // phase-3 uniforms, consumed late
            b2v = *(const floatx4*)(b2 + m * H_DIM + w * 64 + c16 * 4);
            w3v = *(const floatx4*)(w3 + m * H_DIM + w * 64 + c16 * 4);
            b3v = b3[m];
        }

        // ---- epilogue: bias+relu+cvt, 8B ds_write, 16B-chunk XOR swizzle ----
#pragma unroll
        for (int rb = 0; rb < 4; ++rb)
#pragma unroll
            for (int r = 0; r < 4; ++r) {
                float v0 = fmaxf(acc[rb][0][r] + b1v[0], 0.f);
                float v1 = fmaxf(acc[rb][1][r] + b1v[1], 0.f);
                float v2 = fmaxf(acc[rb][2][r] + b1v[2], 0.f);
                float v3 = fmaxf(acc[rb][3][r] + b1v[3], 0.f);
                uint2v u2; u2[0] = pkbf(v0, v1); u2[1] = pkbf(v2, v3);
                int row = rb * 16 + q * 4 + r;
                int chunk = (w * 8 + (c16 >> 1)) ^ (row & 7);
                *(uint2v*)((char*)&h1s[0] + row * 512 + chunk * 16 + (c16 & 1) * 8) = u2;
            }
        __syncthreads();                          // B1/B3: h1 ready

        // ---- Phase 2: h2 = relu(h1 @ W2 + b2); ping-pong bv ----
#pragma unroll
        for (int rb = 0; rb < 4; ++rb)
#pragma unroll
            for (int nb = 0; nb < 4; ++nb)
                acc[rb][nb] = (floatx4){0.f, 0.f, 0.f, 0.f};
#pragma unroll
        for (int kb = 0; kb < 8; ++kb) {
            if (kb < 7) {
#pragma unroll
                for (int nb = 0; nb < 4; ++nb)
                    bv[(kb + 1) & 1][nb] = *(const short8*)(w2p + nb * H_DIM + (kb + 1) * 32);
            }
            short8 av[4];
#pragma unroll
            for (int rb = 0; rb < 4; ++rb)
                av[rb] = *(const short8*)((char*)&h1s[0] + (rb * 16 + c16) * 512
                                          + (((kb * 4 + q) ^ sw) * 16));
            __builtin_amdgcn_s_setprio(1);
#pragma unroll
            for (int nb = 0; nb < 4; ++nb)
#pragma unroll
                for (int rb = 0; rb < 4; ++rb)
                    acc[rb][nb] = __builtin_amdgcn_mfma_f32_16x16x32_bf16(
                        av[rb], bv[kb & 1][nb], acc[rb][nb], 0, 0, 0);
            __builtin_amdgcn_s_setprio(0);
        }

        // ---- Phase 3 fold: p = sum_nb relu(h2)*w3 (acc dies here) ----
#pragma unroll
        for (int rb = 0; rb < 4; ++rb)
#pragma unroll
            for (int r = 0; r < 4; ++r) p[t][rb][r] = 0.f;
#pragma unroll
        for (int rb = 0; rb < 4; ++rb)
#pragma unroll
            for (int nb = 0; nb < 4; ++nb)
#pragma unroll
                for (int r = 0; r < 4; ++r) {
                    float v = fmaxf(acc[rb][nb][r] + b2v[nb], 0.f);
                    p[t][rb][r] += v * w3v[nb];
                }

        if (t == 0) {
            // acc DEAD: pin t1's x loads below the fold (R3/R5 spill lesson);
            // HBM/L3 latency hides under the shfl tree + barrier.
            __builtin_amdgcn_sched_barrier(0);
#pragma unroll
            for (int rb = 0; rb < 4; ++rb)
#pragma unroll
                for (int kb = 0; kb < 2; ++kb) {
                    const float* xp = xrow0 + 64 * IN_DIM
                                      + (rb * 16 + c16) * IN_DIM + kb * 32 + q * 8;
                    xr[rb][kb][0] = *(const float4*)xp;
                    xr[rb][kb][1] = *(const float4*)(xp + 4);
                }
        }

        // ---- shfl tree over the 16 col-lanes ----
#pragma unroll
        for (int off = 1; off < 16; off <<= 1)
#pragma unroll
            for (int rb = 0; rb < 4; ++rb)
#pragma unroll
                for (int r = 0; r < 4; ++r)
                    p[t][rb][r] += __shfl_xor(p[t][rb][r], off);

        if (t == 0)
            __syncthreads();                      // B2: all h1 reads done before t1 epi
    }

    // ---- out = p + b3: red slab, one barrier, 128-thread tail ----
    if (c16 == 0) {
#pragma unroll
        for (int t = 0; t < 2; ++t)
#pragma unroll
            for (int rb = 0; rb < 4; ++rb)
#pragma unroll
                for (int r = 0; r < 4; ++r)
                    red[t * 256 + w * 64 + rb * 16 + q * 4 + r] = p[t][rb][r];
    }
    __syncthreads();                              // B4
    if (tid < 128) {
        int t = tid >> 6, rr = tid & 63;
        const float* rt = red + t * 256;
        float s = rt[rr] + rt[64 + rr] + rt[128 + rr] + rt[192 + rr] + b3v;
        out[(size_t)m * BBATCH + (tile0 + t) * 64 + rr] = s;
    }
}

extern "C" void kernel_launch(void* const* d_in, const int* in_sizes, int n_in,
                              void* d_out, int out_size, void* d_ws, size_t ws_size,
                              hipStream_t stream) {
    const float* xs = (const float*)d_in[0];
    const float* W1 = (const float*)d_in[1];
    const float* b1 = (const float*)d_in[2];
    const float* W2 = (const float*)d_in[3];
    const float* b2 = (const float*)d_in[4];
    const float* W3 = (const float*)d_in[5];
    const float* b3 = (const float*)d_in[6];
    float* out = (float*)d_out;

    unsigned short* w1t = (unsigned short*)d_ws;                    // 2 MB
    unsigned short* w2t = w1t + (size_t)NMODELS * H_DIM * IN_DIM;   // 8.4 MB

    prep_weights<<<256 + NMODELS * 16, 256, 0, stream>>>(W1, W2, w1t, w2t);
    mlp_fused<<<NMODELS * (BBATCH / 128), 256, 0, stream>>>(xs, w1t, b1, w2t, b2, W3, b3, out);
}

// Round 11
// 179.799 us; speedup vs baseline: 1.2396x; 1.2396x over previous
//
#include <hip/hip_runtime.h>
#include <hip/hip_bf16.h>

#define NMODELS 64
#define BBATCH  4096
#define IN_DIM  64
#define H_DIM   256

typedef __attribute__((ext_vector_type(8))) short short8;
typedef __attribute__((ext_vector_type(4))) float floatx4;
typedef __attribute__((ext_vector_type(4))) unsigned int uint4v;
typedef __attribute__((ext_vector_type(2))) unsigned int uint2v;

__device__ __forceinline__ unsigned short f2bf(float f) {   // prep only
    unsigned int u = __builtin_bit_cast(unsigned int, f);
    return (unsigned short)((u + 0x8000u) >> 16);
}
// packed fp32x2 -> bf16x2 (v_cvt_pk_bf16_f32 on gfx950), RNE
__device__ __forceinline__ unsigned int pkbf(float a, float b) {
    __hip_bfloat162 h = __float22bfloat162_rn(make_float2(a, b));
    unsigned int u;
    __builtin_memcpy(&u, &h, 4);
    return u;
}

// Transpose+cvt: W1 [M][64][256]->w1t [M][256][64] bf16 (blocks 0..255)
//                W2 [M][256][256]->w2t [M][256][256] bf16 (blocks 256..1279)
__global__ __launch_bounds__(256) void prep_weights(const float* __restrict__ W1,
                                                    const float* __restrict__ W2,
                                                    unsigned short* __restrict__ w1t,
                                                    unsigned short* __restrict__ w2t) {
    __shared__ float lds[64][65];
    const int bid = blockIdx.x;
    const float* src;
    unsigned short* dst;
    int K, N, m, kb, nb;
    if (bid < 256) {
        m = bid >> 2; kb = 0; nb = bid & 3; K = IN_DIM; N = H_DIM;
        src = W1; dst = w1t;
    } else {
        int t = bid - 256;
        m = t >> 4; kb = (t >> 2) & 3; nb = t & 3; K = H_DIM; N = H_DIM;
        src = W2; dst = w2t;
    }
    const float* s = src + ((size_t)m * K + (size_t)kb * 64) * N + nb * 64;
    const int tid = threadIdx.x;
    const int r = tid >> 4, c4 = (tid & 15) * 4;
#pragma unroll
    for (int p = 0; p < 4; ++p) {
        int row = p * 16 + r;                      // k-local 0..63
        float4 v = *(const float4*)(s + (size_t)row * N + c4);
        lds[row][c4] = v.x; lds[row][c4 + 1] = v.y;
        lds[row][c4 + 2] = v.z; lds[row][c4 + 3] = v.w;
    }
    __syncthreads();
    unsigned short* dbase = dst + ((size_t)m * N + (size_t)nb * 64) * K + kb * 64;
    const int j = tid & 7;                         // k-chunk 0..7
#pragma unroll
    for (int it = 0; it < 2; ++it) {
        int n = it * 32 + (tid >> 3);              // n-local 0..63
        unsigned short tmp[8];
#pragma unroll
        for (int e = 0; e < 8; ++e) tmp[e] = f2bf(lds[j * 8 + e][n]);
        *(short8*)(dbase + (size_t)n * K + j * 8) = *(const short8*)tmp;
    }
}

// Fused 3-layer MLP, T=2 tiles/WG, 2 WG/CU (R9 champion, 84us) + phase-2
// own-slice rotation. Swizzle algebra: h1 k-slice kb (logical chunks
// kb*4+q in [8w,8w+8)) is written ENTIRELY by wave w=kb>>1, across all 64
// rows. So wave w can start phase 2 at kb=2w,2w+1 (its own data, same-wave
// LDS RAW ordered by lgkmcnt) with NO barrier, deferring __syncthreads to
// the first foreign slice (i==2). The barrier drain + inter-wave epilogue
// skew hide under 64 MFMAs + bv prefetch instead of idling all 8 waves/CU.
// Occupancy-raising restructures (T=1, row-split, T=2-seq, persistent) all
// measured WORSE (131-167us): per-wave B-reuse + register headroom bind,
// not occupancy. Keeps: XCD-bijective swizzle (84us win, R9), setprio,
// swizzled h1 LDS, separate red slab, sunk phase-3 uniforms.
__global__ __launch_bounds__(256, 2) void mlp_fused(
    const float* __restrict__ xs,
    const unsigned short* __restrict__ w1t,   // [M][H][IN] bf16
    const float* __restrict__ b1,
    const unsigned short* __restrict__ w2t,   // [M][H][H] bf16 (n-major)
    const float* __restrict__ b2,
    const float* __restrict__ w3,             // [M][H]
    const float* __restrict__ b3,             // [M]
    float* __restrict__ out)                  // [M][B]
{
    __shared__ unsigned short h1s[2][64 * 256];   // 64 KB
    __shared__ float red[2 * 256];                // 2 KB separate slab

    const int bid = blockIdx.x;
    const int wg  = (bid & 7) * 256 + (bid >> 3); // XCD-bijective (2048 = 8*256)
    const int m     = wg >> 5;
    const int tile0 = (wg & 31) * 2;              // this WG: tiles tile0, tile0+1
    const int tid = threadIdx.x;
    const int w   = tid >> 6;
    const int lane = tid & 63;
    const int q   = lane >> 4;
    const int c16 = lane & 15;
    const int sw  = c16 & 7;

    // b1 needed in phase-1 epilogue; hoist only it (b2/w3/b3 sunk below)
    floatx4 b1v = *(const floatx4*)(b1 + m * H_DIM + w * 64 + c16 * 4);

    // ---------------- Phase 1: h1[t] = relu(x[t] @ W1 + b1), t=0,1 ----------------
    const float* xrow0 = xs + ((size_t)m * BBATCH + (size_t)tile0 * 64) * IN_DIM;
    const unsigned short* w1p = w1t + (size_t)m * (H_DIM * IN_DIM)
                                + (w * 64 + c16 * 4) * IN_DIM + q * 8;
    const unsigned short* w2p = w2t + (size_t)m * (H_DIM * H_DIM)
                                + (w * 64 + c16 * 4) * H_DIM + q * 8;

    short8 ax[2][4][2];
#pragma unroll
    for (int t = 0; t < 2; ++t)
#pragma unroll
        for (int rb = 0; rb < 4; ++rb)
#pragma unroll
            for (int kb = 0; kb < 2; ++kb) {
                const float* xp = xrow0 + (size_t)t * 64 * IN_DIM
                                  + (rb * 16 + c16) * IN_DIM + kb * 32 + q * 8;
                float4 v0 = *(const float4*)xp;
                float4 v1 = *(const float4*)(xp + 4);
                uint4v u;
                u[0] = pkbf(v0.x, v0.y); u[1] = pkbf(v0.z, v0.w);
                u[2] = pkbf(v1.x, v1.y); u[3] = pkbf(v1.z, v1.w);
                ax[t][rb][kb] = __builtin_bit_cast(short8, u);
            }

    floatx4 acc[2][4][4];
#pragma unroll
    for (int t = 0; t < 2; ++t)
#pragma unroll
        for (int rb = 0; rb < 4; ++rb)
#pragma unroll
            for (int nb = 0; nb < 4; ++nb)
                acc[t][rb][nb] = (floatx4){0.f, 0.f, 0.f, 0.f};

    {
        short8 bw[2][4];                          // shared across both tiles
#pragma unroll
        for (int kb = 0; kb < 2; ++kb)
#pragma unroll
            for (int nb = 0; nb < 4; ++nb)
                bw[kb][nb] = *(const short8*)(w1p + nb * IN_DIM + kb * 32);
        __builtin_amdgcn_s_setprio(1);
#pragma unroll
        for (int t = 0; t < 2; ++t)
#pragma unroll
            for (int kb = 0; kb < 2; ++kb)
#pragma unroll
                for (int nb = 0; nb < 4; ++nb)
#pragma unroll
                    for (int rb = 0; rb < 4; ++rb)
                        acc[t][rb][nb] = __builtin_amdgcn_mfma_f32_16x16x32_bf16(
                            ax[t][rb][kb], bw[kb][nb], acc[t][rb][nb], 0, 0, 0);
        __builtin_amdgcn_s_setprio(0);
    }

    // Prefetch phase-2 B for the ROTATED sequence start: kb = 2w, 2w+1
    // (own-slice first). Latency overlaps epilogue cvt/ds_write.
    short8 bv[3][4];
#pragma unroll
    for (int nb = 0; nb < 4; ++nb)
        bv[0][nb] = *(const short8*)(w2p + nb * H_DIM + (2 * w) * 32);
#pragma unroll
    for (int nb = 0; nb < 4; ++nb)
        bv[1][nb] = *(const short8*)(w2p + nb * H_DIM + (2 * w + 1) * 32);

    // phase-3-only uniform loads: issue here so latency hides under epilogue
    // + phase 2 (consumed only after phase 2).
    floatx4 b2v = *(const floatx4*)(b2 + m * H_DIM + w * 64 + c16 * 4);
    floatx4 w3v = *(const floatx4*)(w3 + m * H_DIM + w * 64 + c16 * 4);
    const float b3v = b3[m];

    {   // epilogue: bias+relu+packed cvt, 8B ds_write per (t,rb,r), 16B-chunk XOR swizzle
#pragma unroll
        for (int t = 0; t < 2; ++t)
#pragma unroll
            for (int rb = 0; rb < 4; ++rb)
#pragma unroll
                for (int r = 0; r < 4; ++r) {
                    float v0 = fmaxf(acc[t][rb][0][r] + b1v[0], 0.f);
                    float v1 = fmaxf(acc[t][rb][1][r] + b1v[1], 0.f);
                    float v2 = fmaxf(acc[t][rb][2][r] + b1v[2], 0.f);
                    float v3 = fmaxf(acc[t][rb][3][r] + b1v[3], 0.f);
                    uint2v u2; u2[0] = pkbf(v0, v1); u2[1] = pkbf(v2, v3);
                    int row = rb * 16 + q * 4 + r;
                    int chunk = (w * 8 + (c16 >> 1)) ^ (row & 7);
                    *(uint2v*)((char*)&h1s[t][0] + row * 512 + chunk * 16 + (c16 & 1) * 8) = u2;
                }
    }
    // NO barrier here: first two phase-2 iterations consume own-wave slices.

    // ---------------- Phase 2: h2[t] = relu(h1[t] @ W2 + b2); rotated ----------
#pragma unroll
    for (int t = 0; t < 2; ++t)
#pragma unroll
        for (int rb = 0; rb < 4; ++rb)
#pragma unroll
            for (int nb = 0; nb < 4; ++nb)
                acc[t][rb][nb] = (floatx4){0.f, 0.f, 0.f, 0.f};

#pragma unroll
    for (int i = 0; i < 8; ++i) {
        const int kb  = (2 * w + i) & 7;          // own slices first (i=0,1)
        const int cur = i % 3;
        const int pre = (i + 2) % 3;
        if (i < 6) {                              // keep depth-2 in flight
            const int kbn = (2 * w + i + 2) & 7;
#pragma unroll
            for (int nb = 0; nb < 4; ++nb)
                bv[pre][nb] = *(const short8*)(w2p + nb * H_DIM + kbn * 32);
        }
        if (i == 2)
            __syncthreads();                      // first foreign slice: all
                                                  // epilogue writes now visible
        short8 av[2][4];
#pragma unroll
        for (int t = 0; t < 2; ++t)
#pragma unroll
            for (int rb = 0; rb < 4; ++rb)
                av[t][rb] = *(const short8*)((char*)&h1s[t][0] + (rb * 16 + c16) * 512
                                             + (((kb * 4 + q) ^ sw) * 16));
        __builtin_amdgcn_s_setprio(1);
#pragma unroll
        for (int nb = 0; nb < 4; ++nb)
#pragma unroll
            for (int t = 0; t < 2; ++t)
#pragma unroll
                for (int rb = 0; rb < 4; ++rb)
                    acc[t][rb][nb] = __builtin_amdgcn_mfma_f32_16x16x32_bf16(
                        av[t][rb], bv[cur][nb], acc[t][rb][nb], 0, 0, 0);
        __builtin_amdgcn_s_setprio(0);
    }

    // ---------------- Phase 3: out = h2 @ W3 + b3 (OUT=1), shfl reduce ----------
    float p[2][4][4];
#pragma unroll
    for (int t = 0; t < 2; ++t)
#pragma unroll
        for (int rb = 0; rb < 4; ++rb)
#pragma unroll
            for (int r = 0; r < 4; ++r) p[t][rb][r] = 0.f;
#pragma unroll
    for (int t = 0; t < 2; ++t)
#pragma unroll
        for (int rb = 0; rb < 4; ++rb)
#pragma unroll
            for (int nb = 0; nb < 4; ++nb)
#pragma unroll
                for (int r = 0; r < 4; ++r) {
                    float v = fmaxf(acc[t][rb][nb][r] + b2v[nb], 0.f);
                    p[t][rb][r] += v * w3v[nb];
                }
#pragma unroll
    for (int off = 1; off < 16; off <<= 1)
#pragma unroll
        for (int t = 0; t < 2; ++t)
#pragma unroll
            for (int rb = 0; rb < 4; ++rb)
#pragma unroll
                for (int r = 0; r < 4; ++r)
                    p[t][rb][r] += __shfl_xor(p[t][rb][r], off);

    if (c16 == 0) {                               // red is a separate slab: no
#pragma unroll                                    // pre-write barrier needed
        for (int t = 0; t < 2; ++t)
#pragma unroll
            for (int rb = 0; rb < 4; ++rb)
#pragma unroll
                for (int r = 0; r < 4; ++r)
                    red[t * 256 + w * 64 + rb * 16 + q * 4 + r] = p[t][rb][r];
    }
    __syncthreads();
    if (tid < 128) {
        int t = tid >> 6, rr = tid & 63;
        const float* rt = red + t * 256;
        float s = rt[rr] + rt[64 + rr] + rt[128 + rr] + rt[192 + rr] + b3v;
        out[(size_t)m * BBATCH + (tile0 + t) * 64 + rr] = s;
    }
}

extern "C" void kernel_launch(void* const* d_in, const int* in_sizes, int n_in,
                              void* d_out, int out_size, void* d_ws, size_t ws_size,
                              hipStream_t stream) {
    const float* xs = (const float*)d_in[0];
    const float* W1 = (const float*)d_in[1];
    const float* b1 = (const float*)d_in[2];
    const float* W2 = (const float*)d_in[3];
    const float* b2 = (const float*)d_in[4];
    const float* W3 = (const float*)d_in[5];
    const float* b3 = (const float*)d_in[6];
    float* out = (float*)d_out;

    unsigned short* w1t = (unsigned short*)d_ws;                    // 2 MB
    unsigned short* w2t = w1t + (size_t)NMODELS * H_DIM * IN_DIM;   // 8.4 MB

    prep_weights<<<256 + NMODELS * 16, 256, 0, stream>>>(W1, W2, w1t, w2t);
    mlp_fused<<<NMODELS * (BBATCH / 128), 256, 0, stream>>>(xs, w1t, b1, w2t, b2, W3, b3, out);
}

// Round 12
// 173.977 us; speedup vs baseline: 1.2810x; 1.0335x over previous
//
#include <hip/hip_runtime.h>
#include <hip/hip_bf16.h>

#define NMODELS 64
#define BBATCH  4096
#define IN_DIM  64
#define H_DIM   256

typedef __attribute__((ext_vector_type(8))) short short8;
typedef __attribute__((ext_vector_type(4))) float floatx4;
typedef __attribute__((ext_vector_type(4))) unsigned int uint4v;
typedef __attribute__((ext_vector_type(2))) unsigned int uint2v;

__device__ __forceinline__ unsigned short f2bf(float f) {   // prep only
    unsigned int u = __builtin_bit_cast(unsigned int, f);
    return (unsigned short)((u + 0x8000u) >> 16);
}
// packed fp32x2 -> bf16x2 (v_cvt_pk_bf16_f32 on gfx950), RNE
__device__ __forceinline__ unsigned int pkbf(float a, float b) {
    __hip_bfloat162 h = __float22bfloat162_rn(make_float2(a, b));
    unsigned int u;
    __builtin_memcpy(&u, &h, 4);
    return u;
}

// Transpose+cvt: W1 [M][64][256]->w1t [M][256][64] bf16 (blocks 0..255)
//                W2 [M][256][256]->w2t [M][256][256] bf16 (blocks 256..1279)
__global__ __launch_bounds__(256) void prep_weights(const float* __restrict__ W1,
                                                    const float* __restrict__ W2,
                                                    unsigned short* __restrict__ w1t,
                                                    unsigned short* __restrict__ w2t) {
    __shared__ float lds[64][65];
    const int bid = blockIdx.x;
    const float* src;
    unsigned short* dst;
    int K, N, m, kb, nb;
    if (bid < 256) {
        m = bid >> 2; kb = 0; nb = bid & 3; K = IN_DIM; N = H_DIM;
        src = W1; dst = w1t;
    } else {
        int t = bid - 256;
        m = t >> 4; kb = (t >> 2) & 3; nb = t & 3; K = H_DIM; N = H_DIM;
        src = W2; dst = w2t;
    }
    const float* s = src + ((size_t)m * K + (size_t)kb * 64) * N + nb * 64;
    const int tid = threadIdx.x;
    const int r = tid >> 4, c4 = (tid & 15) * 4;
#pragma unroll
    for (int p = 0; p < 4; ++p) {
        int row = p * 16 + r;                      // k-local 0..63
        float4 v = *(const float4*)(s + (size_t)row * N + c4);
        lds[row][c4] = v.x; lds[row][c4 + 1] = v.y;
        lds[row][c4 + 2] = v.z; lds[row][c4 + 3] = v.w;
    }
    __syncthreads();
    unsigned short* dbase = dst + ((size_t)m * N + (size_t)nb * 64) * K + kb * 64;
    const int j = tid & 7;                         // k-chunk 0..7
#pragma unroll
    for (int it = 0; it < 2; ++it) {
        int n = it * 32 + (tid >> 3);              // n-local 0..63
        unsigned short tmp[8];
#pragma unroll
        for (int e = 0; e < 8; ++e) tmp[e] = f2bf(lds[j * 8 + e][n]);
        *(short8*)(dbase + (size_t)n * K + j * 8) = *(const short8*)tmp;
    }
}

// Fused 3-layer MLP, T=2 tiles/WG, 2 WG/CU (R9 champion, 84us) + phase-3
// rewrite. Issue accounting of R9: MFMA ~20%, VALU ~25%, DS ~15% of CU
// cycles — issue-thin, and phase 3's shfl tree was the largest reducible
// block: 128 ds_permute wave-insts (~770 cyc) + ~400 VALU moves PER WAVE.
// New phase 3: fold p (VALU, unchanged) -> barrier -> each thread scatters
// its 32 partials as 8 ds_write_b128 into a 32 KB chunk-XOR-swizzled slab
// overlaid on h1s (b128 bank floor) -> barrier -> 128 threads sum their
// row's 64 sources directly (4-way b32, one-time) and store. ~4x less DS
// issue in the tail; red slab removed (LDS 64 KB); +1 barrier.
// Failed alternatives (measured): T=1 131us, row-split 167us, T=2-seq 131us,
// persistent 186-207us (spills), phase-2 rotation 86.5us. Occupancy-raising
// loses; per-wave B-reuse + register headroom bind.
__global__ __launch_bounds__(256, 2) void mlp_fused(
    const float* __restrict__ xs,
    const unsigned short* __restrict__ w1t,   // [M][H][IN] bf16
    const float* __restrict__ b1,
    const unsigned short* __restrict__ w2t,   // [M][H][H] bf16 (n-major)
    const float* __restrict__ b2,
    const float* __restrict__ w3,             // [M][H]
    const float* __restrict__ b3,             // [M]
    float* __restrict__ out)                  // [M][B]
{
    __shared__ unsigned short h1s[2][64 * 256];   // 64 KB; phase-3 pslab overlay

    const int bid = blockIdx.x;
    const int wg  = (bid & 7) * 256 + (bid >> 3); // XCD-bijective (2048 = 8*256)
    const int m     = wg >> 5;
    const int tile0 = (wg & 31) * 2;              // this WG: tiles tile0, tile0+1
    const int tid = threadIdx.x;
    const int w   = tid >> 6;
    const int lane = tid & 63;
    const int q   = lane >> 4;
    const int c16 = lane & 15;
    const int sw  = c16 & 7;

    // b1 needed in phase-1 epilogue; hoist only it (b2/w3/b3 sunk below)
    floatx4 b1v = *(const floatx4*)(b1 + m * H_DIM + w * 64 + c16 * 4);

    // ---------------- Phase 1: h1[t] = relu(x[t] @ W1 + b1), t=0,1 ----------------
    const float* xrow0 = xs + ((size_t)m * BBATCH + (size_t)tile0 * 64) * IN_DIM;
    const unsigned short* w1p = w1t + (size_t)m * (H_DIM * IN_DIM)
                                + (w * 64 + c16 * 4) * IN_DIM + q * 8;
    const unsigned short* w2p = w2t + (size_t)m * (H_DIM * H_DIM)
                                + (w * 64 + c16 * 4) * H_DIM + q * 8;

    short8 ax[2][4][2];
#pragma unroll
    for (int t = 0; t < 2; ++t)
#pragma unroll
        for (int rb = 0; rb < 4; ++rb)
#pragma unroll
            for (int kb = 0; kb < 2; ++kb) {
                const float* xp = xrow0 + (size_t)t * 64 * IN_DIM
                                  + (rb * 16 + c16) * IN_DIM + kb * 32 + q * 8;
                float4 v0 = *(const float4*)xp;
                float4 v1 = *(const float4*)(xp + 4);
                uint4v u;
                u[0] = pkbf(v0.x, v0.y); u[1] = pkbf(v0.z, v0.w);
                u[2] = pkbf(v1.x, v1.y); u[3] = pkbf(v1.z, v1.w);
                ax[t][rb][kb] = __builtin_bit_cast(short8, u);
            }

    floatx4 acc[2][4][4];
#pragma unroll
    for (int t = 0; t < 2; ++t)
#pragma unroll
        for (int rb = 0; rb < 4; ++rb)
#pragma unroll
            for (int nb = 0; nb < 4; ++nb)
                acc[t][rb][nb] = (floatx4){0.f, 0.f, 0.f, 0.f};

    {
        short8 bw[2][4];                          // shared across both tiles
#pragma unroll
        for (int kb = 0; kb < 2; ++kb)
#pragma unroll
            for (int nb = 0; nb < 4; ++nb)
                bw[kb][nb] = *(const short8*)(w1p + nb * IN_DIM + kb * 32);
        __builtin_amdgcn_s_setprio(1);
#pragma unroll
        for (int t = 0; t < 2; ++t)
#pragma unroll
            for (int kb = 0; kb < 2; ++kb)
#pragma unroll
                for (int nb = 0; nb < 4; ++nb)
#pragma unroll
                    for (int rb = 0; rb < 4; ++rb)
                        acc[t][rb][nb] = __builtin_amdgcn_mfma_f32_16x16x32_bf16(
                            ax[t][rb][kb], bw[kb][nb], acc[t][rb][nb], 0, 0, 0);
        __builtin_amdgcn_s_setprio(0);
    }

    // Prefetch phase-2 B slots kb=0,1 (h1-independent): L2 latency overlaps
    // the epilogue cvt/ds_write and the barrier drain.
    short8 bv[3][4];
#pragma unroll
    for (int nb = 0; nb < 4; ++nb) bv[0][nb] = *(const short8*)(w2p + nb * H_DIM + 0 * 32);
#pragma unroll
    for (int nb = 0; nb < 4; ++nb) bv[1][nb] = *(const short8*)(w2p + nb * H_DIM + 1 * 32);

    // phase-3-only uniform loads: issue here so latency hides under epilogue
    // + barrier + phase 2 (consumed only after phase 2).
    floatx4 b2v = *(const floatx4*)(b2 + m * H_DIM + w * 64 + c16 * 4);
    floatx4 w3v = *(const floatx4*)(w3 + m * H_DIM + w * 64 + c16 * 4);
    const float b3v = b3[m];

    {   // epilogue: bias+relu+packed cvt, 8B ds_write per (t,rb,r), 16B-chunk XOR swizzle
#pragma unroll
        for (int t = 0; t < 2; ++t)
#pragma unroll
            for (int rb = 0; rb < 4; ++rb)
#pragma unroll
                for (int r = 0; r < 4; ++r) {
                    float v0 = fmaxf(acc[t][rb][0][r] + b1v[0], 0.f);
                    float v1 = fmaxf(acc[t][rb][1][r] + b1v[1], 0.f);
                    float v2 = fmaxf(acc[t][rb][2][r] + b1v[2], 0.f);
                    float v3 = fmaxf(acc[t][rb][3][r] + b1v[3], 0.f);
                    uint2v u2; u2[0] = pkbf(v0, v1); u2[1] = pkbf(v2, v3);
                    int row = rb * 16 + q * 4 + r;
                    int chunk = (w * 8 + (c16 >> 1)) ^ (row & 7);
                    *(uint2v*)((char*)&h1s[t][0] + row * 512 + chunk * 16 + (c16 & 1) * 8) = u2;
                }
    }
    __syncthreads();

    // ---------------- Phase 2: h2[t] = relu(h1[t] @ W2 + b2); pipelined B ----------
#pragma unroll
    for (int t = 0; t < 2; ++t)
#pragma unroll
        for (int rb = 0; rb < 4; ++rb)
#pragma unroll
            for (int nb = 0; nb < 4; ++nb)
                acc[t][rb][nb] = (floatx4){0.f, 0.f, 0.f, 0.f};

#pragma unroll
    for (int kb = 0; kb < 8; ++kb) {
        const int cur = kb % 3;
        const int pre = (kb + 2) % 3;
        if (kb < 6) {                             // keep depth-2 in flight
#pragma unroll
            for (int nb = 0; nb < 4; ++nb)
                bv[pre][nb] = *(const short8*)(w2p + nb * H_DIM + (kb + 2) * 32);
        }
        short8 av[2][4];
#pragma unroll
        for (int t = 0; t < 2; ++t)
#pragma unroll
            for (int rb = 0; rb < 4; ++rb)
                av[t][rb] = *(const short8*)((char*)&h1s[t][0] + (rb * 16 + c16) * 512
                                             + (((kb * 4 + q) ^ sw) * 16));
        __builtin_amdgcn_s_setprio(1);
#pragma unroll
        for (int nb = 0; nb < 4; ++nb)
#pragma unroll
            for (int t = 0; t < 2; ++t)
#pragma unroll
                for (int rb = 0; rb < 4; ++rb)
                    acc[t][rb][nb] = __builtin_amdgcn_mfma_f32_16x16x32_bf16(
                        av[t][rb], bv[cur][nb], acc[t][rb][nb], 0, 0, 0);
        __builtin_amdgcn_s_setprio(0);
    }

    // ---------------- Phase 3: out = h2 @ W3 + b3 (OUT=1) ----------------------
    // Fold (VALU only, no LDS — overlaps other waves' phase-2 tails)
    float p[2][4][4];
#pragma unroll
    for (int t = 0; t < 2; ++t)
#pragma unroll
        for (int rb = 0; rb < 4; ++rb)
#pragma unroll
            for (int r = 0; r < 4; ++r) p[t][rb][r] = 0.f;
#pragma unroll
    for (int t = 0; t < 2; ++t)
#pragma unroll
        for (int rb = 0; rb < 4; ++rb)
#pragma unroll
            for (int nb = 0; nb < 4; ++nb)
#pragma unroll
                for (int r = 0; r < 4; ++r) {
                    float v = fmaxf(acc[t][rb][nb][r] + b2v[nb], 0.f);
                    p[t][rb][r] += v * w3v[nb];
                }

    __syncthreads();   // all h1 reads done -> overlay pslab on h1s

    // Scatter: thread tid owns a 32-float (128 B) region; 8 x ds_write_b128
    // at chunk (t*4+rb) ^ (tid&7) -> b128 bank-floor (each 8-lane group
    // covers all 32 banks).
    {
        float* myreg = (float*)&h1s[0][0] + tid * 32;
#pragma unroll
        for (int t = 0; t < 2; ++t)
#pragma unroll
            for (int rb = 0; rb < 4; ++rb) {
                int c = t * 4 + rb;
                float4 v4 = make_float4(p[t][rb][0], p[t][rb][1],
                                        p[t][rb][2], p[t][rb][3]);
                *(float4*)(myreg + (((c ^ (tid & 7)) << 2))) = v4;
            }
    }
    __syncthreads();

    // Gather: 128 threads, one output row each. Row (t, rb,q0,r) sums 64
    // sources: threads {w4*64 + q0*16 + cc}, value v = t*16+rb*4+r at
    // chunk (v>>2) ^ (src&7), word v&3. src&7 == cc&7 (q0*16 ≡ 0 mod 8).
    if (tid < 128) {
        const int t  = tid >> 6, row = tid & 63;
        const int rb = row >> 4, q0 = (row >> 2) & 3, r = row & 3;
        const int v  = t * 16 + rb * 4 + r;
        const int c  = v >> 2, j = v & 3;
        const float* pslab = (const float*)&h1s[0][0];
        float sacc[4] = {0.f, 0.f, 0.f, 0.f};
#pragma unroll
        for (int w4 = 0; w4 < 4; ++w4)
#pragma unroll
            for (int cc = 0; cc < 16; ++cc) {
                int src = w4 * 64 + q0 * 16 + cc;
                sacc[w4] += pslab[src * 32 + ((c ^ (cc & 7)) << 2) + j];
            }
        float s = (sacc[0] + sacc[1]) + (sacc[2] + sacc[3]) + b3v;
        out[(size_t)m * BBATCH + (size_t)(tile0 + t) * 64 + row] = s;
    }
}

extern "C" void kernel_launch(void* const* d_in, const int* in_sizes, int n_in,
                              void* d_out, int out_size, void* d_ws, size_t ws_size,
                              hipStream_t stream) {
    const float* xs = (const float*)d_in[0];
    const float* W1 = (const float*)d_in[1];
    const float* b1 = (const float*)d_in[2];
    const float* W2 = (const float*)d_in[3];
    const float* b2 = (const float*)d_in[4];
    const float* W3 = (const float*)d_in[5];
    const float* b3 = (const float*)d_in[6];
    float* out = (float*)d_out;

    unsigned short* w1t = (unsigned short*)d_ws;                    // 2 MB
    unsigned short* w2t = w1t + (size_t)NMODELS * H_DIM * IN_DIM;   // 8.4 MB

    prep_weights<<<256 + NMODELS * 16, 256, 0, stream>>>(W1, W2, w1t, w2t);
    mlp_fused<<<NMODELS * (BBATCH / 128), 256, 0, stream>>>(xs, w1t, b1, w2t, b2, W3, b3, out);
}